// Round 1
// baseline (15.596 us; speedup 1.0000x reference)
//
#include <hip/hip_runtime.h>
#include <math.h>

// Shapes fixed by setup_inputs(): rep_anchor [B,M,D] f32, rep_pos/neg [B,D] f32.
constexpr int B = 16;
constexpr int M = 2048;
constexpr int D = 256;
constexpr float MARGIN = 5.0f;

// Work decomposition: CHUNKS blocks per batch element.
constexpr int CHUNKS = 64;                  // blocks per batch
constexpr int ROWS_PER_BLOCK = M / CHUNKS;  // 32 rows
// Block = 256 threads = 4 waves. One wave processes one full row (D=256
// floats) per iteration: 64 lanes x float4 = 256 elements = 1 KiB coalesced.

__global__ __launch_bounds__(256) void cross_partial_kernel(
    const float* __restrict__ anchor,   // [B*M*D]
    const float* __restrict__ pos,      // [B*D]
    const float* __restrict__ neg,      // [B*D]
    float* __restrict__ partial)        // [B*CHUNKS*2] (sum_pos, sum_neg)
{
    const int blk   = blockIdx.x;
    const int b     = blk / CHUNKS;
    const int chunk = blk % CHUNKS;
    const int lane  = threadIdx.x & 63;
    const int wave  = threadIdx.x >> 6;  // 0..3

    // Per-lane slice of pos/neg rows (loaded once, reused for all rows).
    const float4 p4 = *reinterpret_cast<const float4*>(pos + (size_t)b * D + lane * 4);
    const float4 n4 = *reinterpret_cast<const float4*>(neg + (size_t)b * D + lane * 4);

    float accp = 0.0f, accn = 0.0f;
    const int row0 = chunk * ROWS_PER_BLOCK;

    for (int r = wave; r < ROWS_PER_BLOCK; r += 4) {
        const float* arow = anchor + ((size_t)b * M + row0 + r) * (size_t)D;
        const float4 a4 = *reinterpret_cast<const float4*>(arow + lane * 4);

        float t, dp = 0.0f, dn = 0.0f;
        t = a4.x - p4.x; dp = fmaf(t, t, dp);
        t = a4.y - p4.y; dp = fmaf(t, t, dp);
        t = a4.z - p4.z; dp = fmaf(t, t, dp);
        t = a4.w - p4.w; dp = fmaf(t, t, dp);
        t = a4.x - n4.x; dn = fmaf(t, t, dn);
        t = a4.y - n4.y; dn = fmaf(t, t, dn);
        t = a4.z - n4.z; dn = fmaf(t, t, dn);
        t = a4.w - n4.w; dn = fmaf(t, t, dn);

        // Butterfly reduce across the 64-lane wave.
        #pragma unroll
        for (int m = 32; m; m >>= 1) {
            dp += __shfl_xor(dp, m, 64);
            dn += __shfl_xor(dn, m, 64);
        }
        // dp, dn >= 0 exactly (direct squared-diff form), plain sqrt is safe.
        accp += sqrtf(dp);
        accn += sqrtf(dn);
    }

    __shared__ float sp[4], sn[4];
    if (lane == 0) { sp[wave] = accp; sn[wave] = accn; }
    __syncthreads();
    if (threadIdx.x == 0) {
        const float tp = sp[0] + sp[1] + sp[2] + sp[3];
        const float tn = sn[0] + sn[1] + sn[2] + sn[3];
        partial[((size_t)b * CHUNKS + chunk) * 2 + 0] = tp;
        partial[((size_t)b * CHUNKS + chunk) * 2 + 1] = tn;
    }
}

// One wave: lanes 0..B-1 each reduce their batch's partials, apply the
// triplet expression (ed_self cancels algebraically), reduce mean.
__global__ __launch_bounds__(64) void finalize_kernel(
    const float* __restrict__ partial, float* __restrict__ out)
{
    const int lane = threadIdx.x;  // 0..63
    float loss = 0.0f;
    if (lane < B) {
        float tp = 0.0f, tn = 0.0f;
        for (int c = 0; c < CHUNKS; ++c) {
            tp += partial[((size_t)lane * CHUNKS + c) * 2 + 0];
            tn += partial[((size_t)lane * CHUNKS + c) * 2 + 1];
        }
        const float d = (2.0f / (float)M) * (tp - tn) + MARGIN;
        loss = d > 0.0f ? d : 0.0f;
    }
    #pragma unroll
    for (int m = 32; m; m >>= 1) loss += __shfl_xor(loss, m, 64);
    if (lane == 0) out[0] = loss / (float)B;
}

extern "C" void kernel_launch(void* const* d_in, const int* in_sizes, int n_in,
                              void* d_out, int out_size, void* d_ws, size_t ws_size,
                              hipStream_t stream) {
    const float* anchor = (const float*)d_in[0];  // [B, M, D]
    const float* pos    = (const float*)d_in[1];  // [B, D]
    const float* neg    = (const float*)d_in[2];  // [B, D]
    float* out = (float*)d_out;
    float* partial = (float*)d_ws;  // B*CHUNKS*2 floats = 8 KiB, written fully every call

    cross_partial_kernel<<<B * CHUNKS, 256, 0, stream>>>(anchor, pos, neg, partial);
    finalize_kernel<<<1, 64, 0, stream>>>(partial, out);
}